// Round 1
// baseline (45.452 us; speedup 1.0000x reference)
//
#include <hip/hip_runtime.h>

#define NN   16384
#define CIN  64
#define COUT 64
#define KW   257
#define NOUT (NN - KW + 1)   // 16128
#define BM   256
#define NKCH 8

typedef __attribute__((ext_vector_type(8))) short short8;
typedef __attribute__((ext_vector_type(8))) unsigned short ushortx8;
typedef __attribute__((ext_vector_type(4))) float floatx4;
typedef unsigned short ushort_t;

__device__ __forceinline__ ushort_t f2bf(float f) {
  union { float f; unsigned u; } c; c.f = f;
  unsigned u = c.u;
  return (ushort_t)((u + 0x7FFFu + ((u >> 16) & 1u)) >> 16);
}
__device__ __forceinline__ float bf2f(ushort_t h) {
  union { unsigned u; float f; } c; c.u = ((unsigned)h) << 16;
  return c.f;
}

// async 16B/lane global->LDS copy. lds base must be wave-uniform; HW adds lane*16.
__device__ __forceinline__ void cp16(const void* g, void* l) {
  auto gp = (const __attribute__((address_space(1))) unsigned int*)(unsigned long long)(uintptr_t)g;
  auto lp = (__attribute__((address_space(3))) unsigned int*)(unsigned int)(uintptr_t)l;
  __builtin_amdgcn_global_load_lds(gp, lp, 16, 0, 0);
}

// prep: x -> bf16 pre-swizzled [16384][64]; kernel -> bf16 flipped+pre-swizzled
// wsz[t][co][ci] = kernel[256-t][co][ci], 16B chunks XORed by (row&7).
// grid exactly 1026*256 = 262656 chunks (x: 131072, w: 131584), 16B out each.
__global__ void prep_convert(const float* __restrict__ x, const float* __restrict__ w,
                             ushort_t* __restrict__ xs, ushort_t* __restrict__ wsz) {
  const int c = blockIdx.x * blockDim.x + threadIdx.x;
  const float* src;
  ushort_t* dst;
  if (c < 131072) {
    const int row = c >> 3, ch = c & 7;
    src = x + (size_t)row * 64 + ((ch ^ (row & 7)) << 3);
    dst = xs + (size_t)row * 64 + (ch << 3);
  } else {
    const int c2 = c - 131072;
    const int t = c2 >> 9, r = (c2 >> 3) & 63, ch = c2 & 7;
    src = w + (size_t)(256 - t) * 4096 + r * 64 + ((ch ^ (r & 7)) << 3);
    dst = wsz + (size_t)t * 4096 + r * 64 + (ch << 3);
  }
  float4 v0 = *(const float4*)src;
  float4 v1 = *(const float4*)(src + 4);
  ushortx8 o;
  o[0] = f2bf(v0.x); o[1] = f2bf(v0.y); o[2] = f2bf(v0.z); o[3] = f2bf(v0.w);
  o[4] = f2bf(v1.x); o[5] = f2bf(v1.y); o[6] = f2bf(v1.z); o[7] = f2bf(v1.w);
  *(ushortx8*)dst = o;
}

__global__ __launch_bounds__(256, 2) void conv_gemm(
    const ushort_t* __restrict__ xs, const ushort_t* __restrict__ wsz,
    ushort_t* __restrict__ part) {
  __shared__ __align__(128) char smem[288 * 128 + 2 * 16384];  // 69632 B
  char* Alds = smem;
  char* Wlds = smem + 288 * 128;

  const int tid  = threadIdx.x;
  const int lane = tid & 63;
  const int w    = tid >> 6;
  const int lr   = lane & 15;
  const int lh   = lane >> 4;

  const int mblk = blockIdx.x;            // 0..62
  const int g    = blockIdx.y;            // 0..7
  const int n0   = mblk * BM;
  const int t0   = (g * KW) / NKCH;       // multiples of 32
  const int t1   = ((g + 1) * KW) / NKCH;
  const int Tc   = t1 - t0;               // 32 (33 for g=7)
  const int NCf  = Tc >> 1;               // 16
  const bool odd = Tc & 1;

  // ---- prologue: async-stage A (288 rows = 36 KB) + W chunk 0 (2 t = 16 KB)
  const ushort_t* agbase = xs + (size_t)(n0 + t0) * 64;
#pragma unroll
  for (int i = 0; i < 9; ++i)
    cp16(agbase + ((w * 9 + i) << 9) + lane * 8, Alds + ((w * 9 + i) << 10));

  const ushort_t* wgbase = wsz + (size_t)t0 * 4096;
#pragma unroll
  for (int s = 0; s < 2; ++s)
#pragma unroll
    for (int i = 0; i < 2; ++i)
      cp16(wgbase + (size_t)s * 4096 + ((w * 2 + i) << 9) + lane * 8,
           Wlds + s * 8192 + (w * 2 + i) * 1024);
  __syncthreads();   // full drain once: A + chunk0 resident

  floatx4 acc[4][4];
#pragma unroll
  for (int m = 0; m < 4; ++m)
#pragma unroll
    for (int nb = 0; nb < 4; ++nb)
      acc[m][nb] = (floatx4){0.f, 0.f, 0.f, 0.f};

  // one phase = 8 ds_read_b128 -> bar -> lgkm(0) -> 16 MFMA (setprio) -> bar
  auto phase = [&](int ttL, int kk, const char* Wl) {
    short8 a[4], b[4];
#pragma unroll
    for (int m = 0; m < 4; ++m) {
      const int row = ttL + w * 64 + m * 16 + lr;          // < 288
      a[m] = *(const short8*)(Alds + row * 128 + (((lh + 4 * kk) ^ (row & 7)) << 4));
    }
#pragma unroll
    for (int nb = 0; nb < 4; ++nb) {
      const int rw = nb * 16 + lr;
      b[nb] = *(const short8*)(Wl + rw * 128 + (((lh + 4 * kk) ^ (rw & 7)) << 4));
    }
    __builtin_amdgcn_s_barrier();
    asm volatile("s_waitcnt lgkmcnt(0)" ::: "memory");
    __builtin_amdgcn_sched_barrier(0);
    __builtin_amdgcn_s_setprio(1);
#pragma unroll
    for (int m = 0; m < 4; ++m)
#pragma unroll
      for (int nb = 0; nb < 4; ++nb)
        acc[m][nb] = __builtin_amdgcn_mfma_f32_16x16x32_bf16(a[m], b[nb], acc[m][nb], 0, 0, 0);
    __builtin_amdgcn_s_setprio(0);
    __builtin_amdgcn_s_barrier();
  };

  for (int cc = 0; cc < NCf; ++cc) {
    const int buf = cc & 1;
    // issue next chunk into buf^1 (safe: all waves finished reading buf^1 at
    // the previous iteration's trailing barrier), then wait ONLY for the 4
    // loads issued one iteration ago (the current buf) — counted vmcnt, never
    // a full drain in the main loop.
    if (cc + 1 < NCf) {
      const ushort_t* wg = wsz + (size_t)(t0 + (cc + 1) * 2) * 4096;
#pragma unroll
      for (int s = 0; s < 2; ++s)
#pragma unroll
        for (int i = 0; i < 2; ++i)
          cp16(wg + (size_t)s * 4096 + ((w * 2 + i) << 9) + lane * 8,
               Wlds + (buf ^ 1) * 16384 + s * 8192 + (w * 2 + i) * 1024);
      asm volatile("s_waitcnt vmcnt(4)" ::: "memory");
    } else if (odd) {
      const ushort_t* wg = wsz + (size_t)(t0 + NCf * 2) * 4096;
#pragma unroll
      for (int i = 0; i < 2; ++i)
        cp16(wg + ((w * 2 + i) << 9) + lane * 8,
             Wlds + (buf ^ 1) * 16384 + (w * 2 + i) * 1024);
      asm volatile("s_waitcnt vmcnt(2)" ::: "memory");
    } else {
      asm volatile("s_waitcnt vmcnt(0)" ::: "memory");
    }
    __builtin_amdgcn_s_barrier();   // buf ready for everyone

    const char* Wl = Wlds + buf * 16384;
    phase(cc * 2,     0, Wl);
    phase(cc * 2,     1, Wl);
    phase(cc * 2 + 1, 0, Wl + 8192);
    phase(cc * 2 + 1, 1, Wl + 8192);
    // phase's trailing barrier (after per-wave lgkmcnt(0)) guarantees all
    // reads of buf are complete before next iter's loads can land in it.
  }
  if (odd) {
    asm volatile("s_waitcnt vmcnt(0)" ::: "memory");
    __builtin_amdgcn_s_barrier();
    const char* Wl = Wlds + (NCf & 1) * 16384;
    phase(Tc - 1, 0, Wl);
    phase(Tc - 1, 1, Wl);
  }

  // epilogue: D layout col=lane&15, row=(lane>>4)*4+r; bf16 partials
  ushort_t* pg = part + (size_t)g * (NOUT * 64);
#pragma unroll
  for (int m = 0; m < 4; ++m)
#pragma unroll
    for (int nb = 0; nb < 4; ++nb)
#pragma unroll
      for (int r = 0; r < 4; ++r) {
        const int row = n0 + w * 64 + m * 16 + lh * 4 + r;
        const int col = nb * 16 + lr;
        pg[(size_t)row * 64 + col] = f2bf(acc[m][nb][r]);
      }
}

// out[n][co] = bias[co] + sum_g part[g][n][co]; one thread per 8 outputs.
__global__ void reduce_out(const ushort_t* __restrict__ part, const float* __restrict__ bias,
                           float* __restrict__ out) {
  const int i = blockIdx.x * blockDim.x + threadIdx.x;   // < NOUT*8
  if (i >= NOUT * 8) return;
  const int colbase = (i & 7) * 8;
  float s[8];
#pragma unroll
  for (int j = 0; j < 8; ++j) s[j] = bias[colbase + j];
#pragma unroll
  for (int gg = 0; gg < NKCH; ++gg) {
    ushortx8 p = *(const ushortx8*)(part + (size_t)gg * (NOUT * 64) + (size_t)i * 8);
#pragma unroll
    for (int j = 0; j < 8; ++j) s[j] += bf2f(p[j]);
  }
  float4 o0 = {s[0], s[1], s[2], s[3]};
  float4 o1 = {s[4], s[5], s[6], s[7]};
  *(float4*)(out + (size_t)i * 8) = o0;
  *(float4*)(out + (size_t)i * 8 + 4) = o1;
}

// correctness fallback if ws is too small
__global__ void naive_conv(const float* __restrict__ x, const float* __restrict__ w,
                           const float* __restrict__ bias, float* __restrict__ out) {
  const int idx = blockIdx.x * blockDim.x + threadIdx.x;
  if (idx >= NOUT * COUT) return;
  const int n = idx / COUT, co = idx % COUT;
  float s = bias[co];
  for (int t = 0; t < KW; ++t) {
    const float* xr = x + (size_t)(n + t) * CIN;
    const float* wr = w + (size_t)(KW - 1 - t) * CIN * COUT + (size_t)co * CIN;
#pragma unroll 8
    for (int ci = 0; ci < CIN; ++ci) s += xr[ci] * wr[ci];
  }
  out[idx] = s;
}

extern "C" void kernel_launch(void* const* d_in, const int* in_sizes, int n_in,
                              void* d_out, int out_size, void* d_ws, size_t ws_size,
                              hipStream_t stream) {
  const float* x    = (const float*)d_in[0];
  const float* kern = (const float*)d_in[1];
  const float* bias = (const float*)d_in[2];
  float* out = (float*)d_out;

  const size_t xs_b   = (size_t)NN * CIN * 2;          // 2 MB
  const size_t ws_b   = (size_t)KW * CIN * COUT * 2;   // 2.06 MB
  const size_t part_b = (size_t)NKCH * NOUT * COUT * 2; // 16.5 MB
  const size_t need   = xs_b + ws_b + part_b;

  if (ws_size < need) {
    naive_conv<<<(NOUT * COUT + 255) / 256, 256, 0, stream>>>(x, kern, bias, out);
    return;
  }

  ushort_t* xs   = (ushort_t*)d_ws;
  ushort_t* wsz  = xs + (size_t)NN * CIN;
  ushort_t* part = wsz + (size_t)KW * CIN * COUT;

  prep_convert<<<1026, 256, 0, stream>>>(x, kern, xs, wsz);
  conv_gemm<<<dim3(NOUT / BM, NKCH), 256, 0, stream>>>(xs, wsz, part);
  reduce_out<<<(NOUT * 8 + 255) / 256, 256, 0, stream>>>(part, bias, out);
}